// Round 2
// baseline (895.190 us; speedup 1.0000x reference)
//
#include <hip/hip_runtime.h>
#include <math.h>

#define NN 100000
#define EE 1600000
#define GG 512
#define INF_ 128
#define HID 64
#define EPS 1e-5f

#define SCAN_CHUNK 1024
#define NB 98   // ceil(NN/SCAN_CHUNK)

// ---------------- CSR build ----------------

__global__ void k_hist(const int* __restrict__ ei, int* __restrict__ cnt) {
    int e = blockIdx.x * 256 + threadIdx.x;
    if (e < EE) atomicAdd(&cnt[ei[EE + e]], 1);
}

// per-block reduce of cnt (1024 elems/block) -> bsum; also dinv = rsqrt(1+cnt)
__global__ void k_block_reduce(const int* __restrict__ cnt, int* __restrict__ bsum,
                               float* __restrict__ dinv) {
    int b = blockIdx.x, t = threadIdx.x;
    int i = b * SCAN_CHUNK + t * 4;
    int c0 = (i     < NN) ? cnt[i]     : 0;
    int c1 = (i + 1 < NN) ? cnt[i + 1] : 0;
    int c2 = (i + 2 < NN) ? cnt[i + 2] : 0;
    int c3 = (i + 3 < NN) ? cnt[i + 3] : 0;
    if (i     < NN) dinv[i]     = rsqrtf(1.f + (float)c0);
    if (i + 1 < NN) dinv[i + 1] = rsqrtf(1.f + (float)c1);
    if (i + 2 < NN) dinv[i + 2] = rsqrtf(1.f + (float)c2);
    if (i + 3 < NN) dinv[i + 3] = rsqrtf(1.f + (float)c3);
    int v = c0 + c1 + c2 + c3;
    for (int d = 32; d > 0; d >>= 1) v += __shfl_down(v, d);
    __shared__ int ws4[4];
    int lane = t & 63, w = t >> 6;
    if (lane == 0) ws4[w] = v;
    __syncthreads();
    if (t == 0) bsum[b] = ws4[0] + ws4[1] + ws4[2] + ws4[3];
}

__global__ void k_scan_bsums(int* __restrict__ bsum, int* __restrict__ offs) {
    __shared__ int tmp[128];
    int t = threadIdx.x;
    for (int i = t; i < NB; i += 128) tmp[i] = bsum[i];
    __syncthreads();
    if (t == 0) {
        int run = 0;
        for (int i = 0; i < NB; ++i) { int v = tmp[i]; tmp[i] = run; run += v; }
        offs[NN] = run;  // == EE
    }
    __syncthreads();
    for (int i = t; i < NB; i += 128) bsum[i] = tmp[i];
}

__global__ void k_scan_apply(const int* __restrict__ cnt, const int* __restrict__ bsum,
                             int* __restrict__ offs, int* __restrict__ cursor) {
    int b = blockIdx.x, t = threadIdx.x;
    int i = b * SCAN_CHUNK + t * 4;
    int c0 = (i     < NN) ? cnt[i]     : 0;
    int c1 = (i + 1 < NN) ? cnt[i + 1] : 0;
    int c2 = (i + 2 < NN) ? cnt[i + 2] : 0;
    int c3 = (i + 3 < NN) ? cnt[i + 3] : 0;
    int s = c0 + c1 + c2 + c3;
    int lane = t & 63, w = t >> 6;
    int v = s;
    for (int d = 1; d < 64; d <<= 1) { int n = __shfl_up(v, d); if (lane >= d) v += n; }
    __shared__ int wsum[4];
    if (lane == 63) wsum[w] = v;
    __syncthreads();
    int wbase = 0;
    for (int q = 0; q < w; ++q) wbase += wsum[q];
    int o0 = bsum[b] + wbase + (v - s);
    int o1 = o0 + c0, o2 = o1 + c1, o3 = o2 + c2;
    if (i     < NN) { offs[i]     = o0; cursor[i]     = o0; }
    if (i + 1 < NN) { offs[i + 1] = o1; cursor[i + 1] = o1; }
    if (i + 2 < NN) { offs[i + 2] = o2; cursor[i + 2] = o2; }
    if (i + 3 < NN) { offs[i + 3] = o3; cursor[i + 3] = o3; }
}

__global__ void k_scatter(const int* __restrict__ ei, int* __restrict__ cursor,
                          const float* __restrict__ dinv, int* __restrict__ col,
                          float* __restrict__ wgt) {
    int e = blockIdx.x * 256 + threadIdx.x;
    if (e >= EE) return;
    int s = ei[e], d = ei[EE + e];
    int p = atomicAdd(&cursor[d], 1);
    col[p] = s;
    wgt[p] = dinv[s];
}

// ---------------- BN constant folding ----------------
__global__ void k_precompute_bn(const float* b1, const float* g1, const float* be1,
                                const float* rm1, const float* rv1,
                                const float* b2, const float* g2, const float* be2,
                                const float* rm2, const float* rv2, float* sc) {
    int l = threadIdx.x;
    float s1 = g1[l] * rsqrtf(rv1[l] + EPS);
    sc[l]       = s1;
    sc[64 + l]  = (b1[l] - rm1[l]) * s1 + be1[l];
    float s2 = g2[l] * rsqrtf(rv2[l] + EPS);
    sc[128 + l] = s2;
    sc[192 + l] = (b2[l] - rm2[l]) * s2 + be2[l];
}

// ---------------- GEMM: [nrows, K] @ [K, 64], LDS-staged X ----------------
// 256 threads, 64 rows/block. X tile staged coalesced into LDS; W column chunk
// held in registers per wave (amortized over 16 rows); X read as LDS broadcast.
template <int K>
__global__ __launch_bounds__(256) void k_gemm_lds(const float* __restrict__ X,
                                                  const float* __restrict__ W,
                                                  float* __restrict__ out, int nrows) {
    __shared__ float Wl[K * 64];
    __shared__ float Xl[64 * K];
    int tid = threadIdx.x;
    for (int i = tid * 4; i < K * 64; i += 1024)
        *(float4*)&Wl[i] = *(const float4*)&W[i];
    int r0 = blockIdx.x * 64;
    const float* Xbase = X + (size_t)r0 * K;
    int limit = (nrows - r0) * K;  // valid floats in this tile
    for (int i = tid * 4; i < 64 * K; i += 1024) {
        float4 v = {0.f, 0.f, 0.f, 0.f};
        if (i + 3 < limit) v = *(const float4*)&Xbase[i];
        *(float4*)&Xl[i] = v;
    }
    __syncthreads();
    int lane = tid & 63, wv = tid >> 6;
    float acc[16];
#pragma unroll
    for (int r = 0; r < 16; ++r) acc[r] = 0.f;
    for (int kb = 0; kb < K; kb += 8) {
        float wreg[8];
#pragma unroll
        for (int j = 0; j < 8; ++j) wreg[j] = Wl[(kb + j) * 64 + lane];
#pragma unroll
        for (int r = 0; r < 16; ++r) {
            const float* xr = &Xl[(wv * 16 + r) * K + kb];
            float4 xa = *(const float4*)(xr);
            float4 xb = *(const float4*)(xr + 4);
            float a = acc[r];
            a = fmaf(xa.x, wreg[0], a);
            a = fmaf(xa.y, wreg[1], a);
            a = fmaf(xa.z, wreg[2], a);
            a = fmaf(xa.w, wreg[3], a);
            a = fmaf(xb.x, wreg[4], a);
            a = fmaf(xb.y, wreg[5], a);
            a = fmaf(xb.z, wreg[6], a);
            a = fmaf(xb.w, wreg[7], a);
            acc[r] = a;
        }
    }
    int gr = r0 + wv * 16;
#pragma unroll
    for (int r = 0; r < 16; ++r)
        if (gr + r < nrows) out[(size_t)(gr + r) * 64 + lane] = acc[r];
}

// ---------------- fused GCN aggregate + selfloop + BN + ReLU (+resid) ------
__global__ void k_gcn_gather(const float* __restrict__ hw, const int* __restrict__ col,
                             const int* __restrict__ offs, const float* __restrict__ wgt,
                             const float* __restrict__ dinv, const float* __restrict__ scale,
                             const float* __restrict__ shift, const float* __restrict__ resid,
                             float* __restrict__ out) {
    int node = blockIdx.x * 4 + (threadIdx.x >> 6);
    if (node >= NN) return;
    int lane = threadIdx.x & 63;
    int e0 = offs[node], e1 = offs[node + 1];
    float di = dinv[node];
    float a0 = 0.f, a1 = 0.f, a2 = 0.f, a3 = 0.f;
    for (int base = e0; base < e1; base += 64) {
        int m = e1 - base; if (m > 64) m = 64;
        int srcv = 0; float wv = 0.f;
        if (lane < m) { srcv = col[base + lane]; wv = wgt[base + lane]; }
        int j = 0;
        for (; j + 4 <= m; j += 4) {
            int s0 = __shfl(srcv, j), s1 = __shfl(srcv, j + 1);
            int s2 = __shfl(srcv, j + 2), s3 = __shfl(srcv, j + 3);
            float n0 = __shfl(wv, j), n1 = __shfl(wv, j + 1);
            float n2 = __shfl(wv, j + 2), n3 = __shfl(wv, j + 3);
            float v0 = hw[s0 * 64 + lane];
            float v1 = hw[s1 * 64 + lane];
            float v2 = hw[s2 * 64 + lane];
            float v3 = hw[s3 * 64 + lane];
            a0 = fmaf(v0, n0, a0); a1 = fmaf(v1, n1, a1);
            a2 = fmaf(v2, n2, a2); a3 = fmaf(v3, n3, a3);
        }
        for (; j < m; ++j) {
            int s = __shfl(srcv, j); float n = __shfl(wv, j);
            a0 = fmaf(hw[s * 64 + lane], n, a0);
        }
    }
    float acc = ((a0 + a1) + (a2 + a3)) * di;
    float v = acc + hw[(long)node * 64 + lane] * di * di;
    v = fmaf(v, scale[lane], shift[lane]);
    v = fmaxf(v, 0.f);
    if (resid) v += resid[(long)node * 64 + lane];
    out[(long)node * 64 + lane] = v;
}

// ---------------- pooling over sorted batch ----------------
__global__ void k_pool(const float* __restrict__ h, const int* __restrict__ batch,
                       float* __restrict__ msum, float* __restrict__ mmax,
                       float* __restrict__ gcnt) {
    int lane = threadIdx.x;  // 64
    int i0 = blockIdx.x * 128;
    int i1 = i0 + 128; if (i1 > NN) i1 = NN;
    int cur = batch[i0];
    float sum = 0.f, mx = 0.f; int c = 0;
    for (int i = i0; i < i1; ++i) {
        int g = batch[i];
        if (g != cur) {
            atomicAdd(&msum[cur * 64 + lane], sum);
            atomicMax((unsigned int*)&mmax[cur * 64 + lane], __float_as_uint(mx));
            if (lane == 0) atomicAdd(&gcnt[cur], (float)c);
            sum = 0.f; mx = 0.f; c = 0; cur = g;
        }
        float v = h[(long)i * 64 + lane];
        sum += v; mx = fmaxf(mx, v); ++c;
    }
    atomicAdd(&msum[cur * 64 + lane], sum);
    atomicMax((unsigned int*)&mmax[cur * 64 + lane], __float_as_uint(mx));
    if (lane == 0) atomicAdd(&gcnt[cur], (float)c);
}

// ---------------- MLP head, one block per graph ----------------
__global__ void k_head(const float* __restrict__ msum, const float* __restrict__ mmax,
                       const float* __restrict__ gcnt,
                       const float* __restrict__ Wh1, const float* __restrict__ bh1,
                       const float* __restrict__ Wh2, const float* __restrict__ bh2,
                       const float* __restrict__ Wh3, const float* __restrict__ bh3,
                       float* __restrict__ out) {
    int g = blockIdx.x, t = threadIdx.x;  // 64 threads
    __shared__ float hg[128];
    __shared__ float z1[64];
    __shared__ float z2[32];
    float c = fmaxf(gcnt[g], 1.f);
    hg[t]      = msum[g * 64 + t] / c;
    hg[64 + t] = mmax[g * 64 + t];
    __syncthreads();
    float acc = bh1[t];
#pragma unroll 8
    for (int k = 0; k < 128; ++k) acc = fmaf(hg[k], Wh1[k * 64 + t], acc);
    z1[t] = fmaxf(acc, 0.f);
    __syncthreads();
    if (t < 32) {
        float a2 = bh2[t];
#pragma unroll 8
        for (int k = 0; k < 64; ++k) a2 = fmaf(z1[k], Wh2[k * 32 + t], a2);
        z2[t] = fmaxf(a2, 0.f);
    }
    __syncthreads();
    if (t == 0) {
        float a3 = bh3[0];
        for (int k = 0; k < 32; ++k) a3 = fmaf(z2[k], Wh3[k], a3);
        out[g] = 1.f / (1.f + expf(-a3));
    }
}

// ---------------- launcher ----------------

static inline size_t alignup(size_t x) { return (x + 255) & ~(size_t)255; }

extern "C" void kernel_launch(void* const* d_in, const int* in_sizes, int n_in,
                              void* d_out, int out_size, void* d_ws, size_t ws_size,
                              hipStream_t stream) {
    const float* x   = (const float*)d_in[0];
    const int*   ei  = (const int*)d_in[1];
    const int*   bat = (const int*)d_in[2];
    const float* W1  = (const float*)d_in[3];
    const float* b1  = (const float*)d_in[4];
    const float* g1  = (const float*)d_in[5];
    const float* be1 = (const float*)d_in[6];
    const float* rm1 = (const float*)d_in[7];
    const float* rv1 = (const float*)d_in[8];
    const float* W2  = (const float*)d_in[9];
    const float* b2  = (const float*)d_in[10];
    const float* g2  = (const float*)d_in[11];
    const float* be2 = (const float*)d_in[12];
    const float* rm2 = (const float*)d_in[13];
    const float* rv2 = (const float*)d_in[14];
    const float* Wh1 = (const float*)d_in[15];
    const float* bh1 = (const float*)d_in[16];
    const float* Wh2 = (const float*)d_in[17];
    const float* bh2 = (const float*)d_in[18];
    const float* Wh3 = (const float*)d_in[19];
    const float* bh3 = (const float*)d_in[20];
    float* out = (float*)d_out;

    char* ws = (char*)d_ws;
    size_t o = 0;
    int*   cnt    = (int*)(ws + o);  o = alignup(o + (NN + 1) * 4);
    int*   offs   = (int*)(ws + o);  o = alignup(o + (NN + 1) * 4);
    int*   cursor = (int*)(ws + o);  o = alignup(o + (size_t)NN * 4);
    int*   col    = (int*)(ws + o);  o = alignup(o + (size_t)EE * 4);
    float* wgt    = (float*)(ws + o); o = alignup(o + (size_t)EE * 4);
    float* dinv   = (float*)(ws + o); o = alignup(o + (size_t)NN * 4);
    int*   bsum   = (int*)(ws + o);  o = alignup(o + 1024);
    float* scb    = (float*)(ws + o); o = alignup(o + 4 * 64 * 4);
    float* msum   = (float*)(ws + o);
    size_t pool_off = o;              o += (size_t)GG * 64 * 4;
    float* mmax   = (float*)(ws + o); o += (size_t)GG * 64 * 4;
    float* gcnt   = (float*)(ws + o); o += (size_t)GG * 4;
    size_t pool_bytes = o - pool_off; o = alignup(o);
    float* hw     = (float*)(ws + o); o = alignup(o + (size_t)NN * 64 * 4);
    float* h      = (float*)(ws + o); o = alignup(o + (size_t)NN * 64 * 4);
    (void)ws_size; (void)n_in; (void)in_sizes; (void)out_size;

    hipMemsetAsync(cnt, 0, (size_t)NN * 4, stream);
    hipMemsetAsync(ws + pool_off, 0, pool_bytes, stream);

    k_precompute_bn<<<1, 64, 0, stream>>>(b1, g1, be1, rm1, rv1, b2, g2, be2, rm2, rv2, scb);
    k_hist<<<EE / 256, 256, 0, stream>>>(ei, cnt);
    k_block_reduce<<<NB, 256, 0, stream>>>(cnt, bsum, dinv);
    k_scan_bsums<<<1, 128, 0, stream>>>(bsum, offs);
    k_scan_apply<<<NB, 256, 0, stream>>>(cnt, bsum, offs, cursor);
    k_scatter<<<EE / 256, 256, 0, stream>>>(ei, cursor, dinv, col, wgt);

    // layer 1
    k_gemm_lds<INF_><<<(NN + 63) / 64, 256, 0, stream>>>(x, W1, hw, NN);
    k_gcn_gather<<<(NN + 3) / 4, 256, 0, stream>>>(hw, col, offs, wgt, dinv,
                                                   scb, scb + 64, nullptr, h);
    // layer 2 (residual, in-place into h)
    k_gemm_lds<HID><<<(NN + 63) / 64, 256, 0, stream>>>(h, W2, hw, NN);
    k_gcn_gather<<<(NN + 3) / 4, 256, 0, stream>>>(hw, col, offs, wgt, dinv,
                                                   scb + 128, scb + 192, h, h);
    // pooling + head
    k_pool<<<(NN + 127) / 128, 64, 0, stream>>>(h, bat, msum, mmax, gcnt);
    k_head<<<GG, 64, 0, stream>>>(msum, mmax, gcnt, Wh1, bh1, Wh2, bh2, Wh3, bh3, out);
}

// Round 3
// 575.599 us; speedup vs baseline: 1.5552x; 1.5552x over previous
//
#include <hip/hip_runtime.h>
#include <math.h>

#define NN 100000
#define EE 1600000
#define GG 512
#define INF_ 128
#define HID 64
#define EPS 1e-5f

#define SCAN_CHUNK 1024
#define NB 98   // ceil(NN/SCAN_CHUNK)

// ---------------- CSR build ----------------

__global__ void k_hist(const int* __restrict__ ei, int* __restrict__ cnt) {
    int e = blockIdx.x * 256 + threadIdx.x;
    if (e < EE) atomicAdd(&cnt[ei[EE + e]], 1);
}

// per-block reduce of cnt (1024 elems/block) -> bsum; also dinv = rsqrt(1+cnt)
__global__ void k_block_reduce(const int* __restrict__ cnt, int* __restrict__ bsum,
                               float* __restrict__ dinv) {
    int b = blockIdx.x, t = threadIdx.x;
    int i = b * SCAN_CHUNK + t * 4;
    int c0 = (i     < NN) ? cnt[i]     : 0;
    int c1 = (i + 1 < NN) ? cnt[i + 1] : 0;
    int c2 = (i + 2 < NN) ? cnt[i + 2] : 0;
    int c3 = (i + 3 < NN) ? cnt[i + 3] : 0;
    if (i     < NN) dinv[i]     = rsqrtf(1.f + (float)c0);
    if (i + 1 < NN) dinv[i + 1] = rsqrtf(1.f + (float)c1);
    if (i + 2 < NN) dinv[i + 2] = rsqrtf(1.f + (float)c2);
    if (i + 3 < NN) dinv[i + 3] = rsqrtf(1.f + (float)c3);
    int v = c0 + c1 + c2 + c3;
    for (int d = 32; d > 0; d >>= 1) v += __shfl_down(v, d);
    __shared__ int ws4[4];
    int lane = t & 63, w = t >> 6;
    if (lane == 0) ws4[w] = v;
    __syncthreads();
    if (t == 0) bsum[b] = ws4[0] + ws4[1] + ws4[2] + ws4[3];
}

__global__ void k_scan_bsums(int* __restrict__ bsum, int* __restrict__ offs) {
    __shared__ int tmp[128];
    int t = threadIdx.x;
    for (int i = t; i < NB; i += 128) tmp[i] = bsum[i];
    __syncthreads();
    if (t == 0) {
        int run = 0;
        for (int i = 0; i < NB; ++i) { int v = tmp[i]; tmp[i] = run; run += v; }
        offs[NN] = run;  // == EE
    }
    __syncthreads();
    for (int i = t; i < NB; i += 128) bsum[i] = tmp[i];
}

__global__ void k_scan_apply(const int* __restrict__ cnt, const int* __restrict__ bsum,
                             int* __restrict__ offs, int* __restrict__ cursor) {
    int b = blockIdx.x, t = threadIdx.x;
    int i = b * SCAN_CHUNK + t * 4;
    int c0 = (i     < NN) ? cnt[i]     : 0;
    int c1 = (i + 1 < NN) ? cnt[i + 1] : 0;
    int c2 = (i + 2 < NN) ? cnt[i + 2] : 0;
    int c3 = (i + 3 < NN) ? cnt[i + 3] : 0;
    int s = c0 + c1 + c2 + c3;
    int lane = t & 63, w = t >> 6;
    int v = s;
    for (int d = 1; d < 64; d <<= 1) { int n = __shfl_up(v, d); if (lane >= d) v += n; }
    __shared__ int wsum[4];
    if (lane == 63) wsum[w] = v;
    __syncthreads();
    int wbase = 0;
    for (int q = 0; q < w; ++q) wbase += wsum[q];
    int o0 = bsum[b] + wbase + (v - s);
    int o1 = o0 + c0, o2 = o1 + c1, o3 = o2 + c2;
    if (i     < NN) { offs[i]     = o0; cursor[i]     = o0; }
    if (i + 1 < NN) { offs[i + 1] = o1; cursor[i + 1] = o1; }
    if (i + 2 < NN) { offs[i + 2] = o2; cursor[i + 2] = o2; }
    if (i + 3 < NN) { offs[i + 3] = o3; cursor[i + 3] = o3; }
}

__global__ void k_scatter(const int* __restrict__ ei, int* __restrict__ cursor,
                          const float* __restrict__ dinv, int* __restrict__ col,
                          float* __restrict__ wgt) {
    int e = blockIdx.x * 256 + threadIdx.x;
    if (e >= EE) return;
    int s = ei[e], d = ei[EE + e];
    int p = atomicAdd(&cursor[d], 1);
    col[p] = s;
    wgt[p] = dinv[s];
}

// ---------------- BN constant folding ----------------
__global__ void k_precompute_bn(const float* b1, const float* g1, const float* be1,
                                const float* rm1, const float* rv1,
                                const float* b2, const float* g2, const float* be2,
                                const float* rm2, const float* rv2, float* sc) {
    int l = threadIdx.x;
    float s1 = g1[l] * rsqrtf(rv1[l] + EPS);
    sc[l]       = s1;
    sc[64 + l]  = (b1[l] - rm1[l]) * s1 + be1[l];
    float s2 = g2[l] * rsqrtf(rv2[l] + EPS);
    sc[128 + l] = s2;
    sc[192 + l] = (b2[l] - rm2[l]) * s2 + be2[l];
}

// ---------------- GEMM: [nrows, K] @ [K, 64], LDS-staged X ----------------
// 256 threads, 64 rows/block, 16 rows/wave, lane = output column.
// X reads from LDS are wave-uniform broadcasts (free); W reads stride-64
// (2-way bank alias = free). kb loop kept rolled to cap register pressure
// (R2 post-mortem: full unroll -> 256 VGPR + 903 MB scratch spill traffic).
template <int K>
__global__ __launch_bounds__(256) void k_gemm_lds(const float* __restrict__ X,
                                                  const float* __restrict__ W,
                                                  float* __restrict__ out, int nrows) {
    __shared__ float Wl[K * 64];
    __shared__ float Xl[64 * K];
    int tid = threadIdx.x;
    for (int i = tid * 4; i < K * 64; i += 1024)
        *(float4*)&Wl[i] = *(const float4*)&W[i];
    int r0 = blockIdx.x * 64;
    const float* Xbase = X + (size_t)r0 * K;
    int limit = (nrows - r0) * K;  // valid floats in this tile
    for (int i = tid * 4; i < 64 * K; i += 1024) {
        float4 v = {0.f, 0.f, 0.f, 0.f};
        if (i + 3 < limit) v = *(const float4*)&Xbase[i];
        *(float4*)&Xl[i] = v;
    }
    __syncthreads();
    int lane = tid & 63, wv = tid >> 6;
    const float* xbase = &Xl[wv * 16 * K];
    float acc[16];
#pragma unroll
    for (int r = 0; r < 16; ++r) acc[r] = 0.f;
#pragma unroll 1
    for (int kb = 0; kb < K; kb += 4) {
        float w0 = Wl[(kb + 0) * 64 + lane];
        float w1 = Wl[(kb + 1) * 64 + lane];
        float w2 = Wl[(kb + 2) * 64 + lane];
        float w3 = Wl[(kb + 3) * 64 + lane];
#pragma unroll
        for (int r = 0; r < 16; ++r) {
            float4 xv = *(const float4*)&xbase[r * K + kb];
            float a = acc[r];
            a = fmaf(xv.x, w0, a);
            a = fmaf(xv.y, w1, a);
            a = fmaf(xv.z, w2, a);
            a = fmaf(xv.w, w3, a);
            acc[r] = a;
        }
    }
    int gr = r0 + wv * 16;
#pragma unroll
    for (int r = 0; r < 16; ++r)
        if (gr + r < nrows) out[(size_t)(gr + r) * 64 + lane] = acc[r];
}

// ---------------- fused GCN aggregate + selfloop + BN + ReLU (+resid) ------
__global__ void k_gcn_gather(const float* __restrict__ hw, const int* __restrict__ col,
                             const int* __restrict__ offs, const float* __restrict__ wgt,
                             const float* __restrict__ dinv, const float* __restrict__ scale,
                             const float* __restrict__ shift, const float* __restrict__ resid,
                             float* __restrict__ out) {
    int node = blockIdx.x * 4 + (threadIdx.x >> 6);
    if (node >= NN) return;
    int lane = threadIdx.x & 63;
    int e0 = offs[node], e1 = offs[node + 1];
    float di = dinv[node];
    float a0 = 0.f, a1 = 0.f, a2 = 0.f, a3 = 0.f;
    for (int base = e0; base < e1; base += 64) {
        int m = e1 - base; if (m > 64) m = 64;
        int srcv = 0; float wv = 0.f;
        if (lane < m) { srcv = col[base + lane]; wv = wgt[base + lane]; }
        int j = 0;
        for (; j + 4 <= m; j += 4) {
            int s0 = __shfl(srcv, j), s1 = __shfl(srcv, j + 1);
            int s2 = __shfl(srcv, j + 2), s3 = __shfl(srcv, j + 3);
            float n0 = __shfl(wv, j), n1 = __shfl(wv, j + 1);
            float n2 = __shfl(wv, j + 2), n3 = __shfl(wv, j + 3);
            float v0 = hw[s0 * 64 + lane];
            float v1 = hw[s1 * 64 + lane];
            float v2 = hw[s2 * 64 + lane];
            float v3 = hw[s3 * 64 + lane];
            a0 = fmaf(v0, n0, a0); a1 = fmaf(v1, n1, a1);
            a2 = fmaf(v2, n2, a2); a3 = fmaf(v3, n3, a3);
        }
        for (; j < m; ++j) {
            int s = __shfl(srcv, j); float n = __shfl(wv, j);
            a0 = fmaf(hw[s * 64 + lane], n, a0);
        }
    }
    float acc = ((a0 + a1) + (a2 + a3)) * di;
    float v = acc + hw[(long)node * 64 + lane] * di * di;
    v = fmaf(v, scale[lane], shift[lane]);
    v = fmaxf(v, 0.f);
    if (resid) v += resid[(long)node * 64 + lane];
    out[(long)node * 64 + lane] = v;
}

// ---------------- pooling over sorted batch ----------------
__global__ void k_pool(const float* __restrict__ h, const int* __restrict__ batch,
                       float* __restrict__ msum, float* __restrict__ mmax,
                       float* __restrict__ gcnt) {
    int lane = threadIdx.x;  // 64
    int i0 = blockIdx.x * 128;
    int i1 = i0 + 128; if (i1 > NN) i1 = NN;
    int cur = batch[i0];
    float sum = 0.f, mx = 0.f; int c = 0;
    for (int i = i0; i < i1; ++i) {
        int g = batch[i];
        if (g != cur) {
            atomicAdd(&msum[cur * 64 + lane], sum);
            atomicMax((unsigned int*)&mmax[cur * 64 + lane], __float_as_uint(mx));
            if (lane == 0) atomicAdd(&gcnt[cur], (float)c);
            sum = 0.f; mx = 0.f; c = 0; cur = g;
        }
        float v = h[(long)i * 64 + lane];
        sum += v; mx = fmaxf(mx, v); ++c;
    }
    atomicAdd(&msum[cur * 64 + lane], sum);
    atomicMax((unsigned int*)&mmax[cur * 64 + lane], __float_as_uint(mx));
    if (lane == 0) atomicAdd(&gcnt[cur], (float)c);
}

// ---------------- MLP head, one block per graph ----------------
__global__ void k_head(const float* __restrict__ msum, const float* __restrict__ mmax,
                       const float* __restrict__ gcnt,
                       const float* __restrict__ Wh1, const float* __restrict__ bh1,
                       const float* __restrict__ Wh2, const float* __restrict__ bh2,
                       const float* __restrict__ Wh3, const float* __restrict__ bh3,
                       float* __restrict__ out) {
    int g = blockIdx.x, t = threadIdx.x;  // 64 threads
    __shared__ float hg[128];
    __shared__ float z1[64];
    __shared__ float z2[32];
    float c = fmaxf(gcnt[g], 1.f);
    hg[t]      = msum[g * 64 + t] / c;
    hg[64 + t] = mmax[g * 64 + t];
    __syncthreads();
    float acc = bh1[t];
#pragma unroll 8
    for (int k = 0; k < 128; ++k) acc = fmaf(hg[k], Wh1[k * 64 + t], acc);
    z1[t] = fmaxf(acc, 0.f);
    __syncthreads();
    if (t < 32) {
        float a2 = bh2[t];
#pragma unroll 8
        for (int k = 0; k < 64; ++k) a2 = fmaf(z1[k], Wh2[k * 32 + t], a2);
        z2[t] = fmaxf(a2, 0.f);
    }
    __syncthreads();
    if (t == 0) {
        float a3 = bh3[0];
        for (int k = 0; k < 32; ++k) a3 = fmaf(z2[k], Wh3[k], a3);
        out[g] = 1.f / (1.f + expf(-a3));
    }
}

// ---------------- launcher ----------------

static inline size_t alignup(size_t x) { return (x + 255) & ~(size_t)255; }

extern "C" void kernel_launch(void* const* d_in, const int* in_sizes, int n_in,
                              void* d_out, int out_size, void* d_ws, size_t ws_size,
                              hipStream_t stream) {
    const float* x   = (const float*)d_in[0];
    const int*   ei  = (const int*)d_in[1];
    const int*   bat = (const int*)d_in[2];
    const float* W1  = (const float*)d_in[3];
    const float* b1  = (const float*)d_in[4];
    const float* g1  = (const float*)d_in[5];
    const float* be1 = (const float*)d_in[6];
    const float* rm1 = (const float*)d_in[7];
    const float* rv1 = (const float*)d_in[8];
    const float* W2  = (const float*)d_in[9];
    const float* b2  = (const float*)d_in[10];
    const float* g2  = (const float*)d_in[11];
    const float* be2 = (const float*)d_in[12];
    const float* rm2 = (const float*)d_in[13];
    const float* rv2 = (const float*)d_in[14];
    const float* Wh1 = (const float*)d_in[15];
    const float* bh1 = (const float*)d_in[16];
    const float* Wh2 = (const float*)d_in[17];
    const float* bh2 = (const float*)d_in[18];
    const float* Wh3 = (const float*)d_in[19];
    const float* bh3 = (const float*)d_in[20];
    float* out = (float*)d_out;

    char* ws = (char*)d_ws;
    size_t o = 0;
    int*   cnt    = (int*)(ws + o);  o = alignup(o + (NN + 1) * 4);
    int*   offs   = (int*)(ws + o);  o = alignup(o + (NN + 1) * 4);
    int*   cursor = (int*)(ws + o);  o = alignup(o + (size_t)NN * 4);
    int*   col    = (int*)(ws + o);  o = alignup(o + (size_t)EE * 4);
    float* wgt    = (float*)(ws + o); o = alignup(o + (size_t)EE * 4);
    float* dinv   = (float*)(ws + o); o = alignup(o + (size_t)NN * 4);
    int*   bsum   = (int*)(ws + o);  o = alignup(o + 1024);
    float* scb    = (float*)(ws + o); o = alignup(o + 4 * 64 * 4);
    float* msum   = (float*)(ws + o);
    size_t pool_off = o;              o += (size_t)GG * 64 * 4;
    float* mmax   = (float*)(ws + o); o += (size_t)GG * 64 * 4;
    float* gcnt   = (float*)(ws + o); o += (size_t)GG * 4;
    size_t pool_bytes = o - pool_off; o = alignup(o);
    float* hw     = (float*)(ws + o); o = alignup(o + (size_t)NN * 64 * 4);
    float* h      = (float*)(ws + o); o = alignup(o + (size_t)NN * 64 * 4);
    (void)ws_size; (void)n_in; (void)in_sizes; (void)out_size;

    hipMemsetAsync(cnt, 0, (size_t)NN * 4, stream);
    hipMemsetAsync(ws + pool_off, 0, pool_bytes, stream);

    k_precompute_bn<<<1, 64, 0, stream>>>(b1, g1, be1, rm1, rv1, b2, g2, be2, rm2, rv2, scb);
    k_hist<<<EE / 256, 256, 0, stream>>>(ei, cnt);
    k_block_reduce<<<NB, 256, 0, stream>>>(cnt, bsum, dinv);
    k_scan_bsums<<<1, 128, 0, stream>>>(bsum, offs);
    k_scan_apply<<<NB, 256, 0, stream>>>(cnt, bsum, offs, cursor);
    k_scatter<<<EE / 256, 256, 0, stream>>>(ei, cursor, dinv, col, wgt);

    // layer 1
    k_gemm_lds<INF_><<<(NN + 63) / 64, 256, 0, stream>>>(x, W1, hw, NN);
    k_gcn_gather<<<(NN + 3) / 4, 256, 0, stream>>>(hw, col, offs, wgt, dinv,
                                                   scb, scb + 64, nullptr, h);
    // layer 2 (residual, in-place into h)
    k_gemm_lds<HID><<<(NN + 63) / 64, 256, 0, stream>>>(h, W2, hw, NN);
    k_gcn_gather<<<(NN + 3) / 4, 256, 0, stream>>>(hw, col, offs, wgt, dinv,
                                                   scb + 128, scb + 192, h, h);
    // pooling + head
    k_pool<<<(NN + 127) / 128, 64, 0, stream>>>(h, bat, msum, mmax, gcnt);
    k_head<<<GG, 64, 0, stream>>>(msum, mmax, gcnt, Wh1, bh1, Wh2, bh2, Wh3, bh3, out);
}

// Round 4
// 436.058 us; speedup vs baseline: 2.0529x; 1.3200x over previous
//
#include <hip/hip_runtime.h>
#include <math.h>

#define NN 100000
#define EE 1600000
#define GG 512
#define INF_ 128
#define HID 64
#define EPS 1e-5f

#define NBUK 391          // ceil(NN/256), bucket = dst >> 8
#define P1_TILES 98       // ceil((EE/4)/4096)

// ---------------- CSR build: 2-level counting sort ----------------
// R3 post-mortem: per-edge atomic scatter had 12x write amplification
// (154 MB for 12.8 MB logical) from cross-XCD line bouncing. Block-aggregated
// bucket sort keeps each output line owned by ~1 block.

__global__ __launch_bounds__(256) void k_bhist(const int* __restrict__ ei,
                                               int* __restrict__ bcnt) {
    __shared__ int h[NBUK];
    int t = threadIdx.x;
    for (int i = t; i < NBUK; i += 256) h[i] = 0;
    __syncthreads();
    const int4* dst4 = (const int4*)(ei + EE);
    int base4 = blockIdx.x * 4096;
    for (int j = 0; j < 16; ++j) {
        int i4 = base4 + j * 256 + t;
        if (i4 < EE / 4) {
            int4 d = dst4[i4];
            atomicAdd(&h[d.x >> 8], 1);
            atomicAdd(&h[d.y >> 8], 1);
            atomicAdd(&h[d.z >> 8], 1);
            atomicAdd(&h[d.w >> 8], 1);
        }
    }
    __syncthreads();
    for (int i = t; i < NBUK; i += 256)
        if (h[i]) atomicAdd(&bcnt[i], h[i]);
}

__global__ void k_bscan(const int* __restrict__ bcnt, int* __restrict__ bbase,
                        int* __restrict__ gcur, int* __restrict__ offs) {
    __shared__ int wsum[8];
    int t = threadIdx.x;  // 512
    int lane = t & 63, w = t >> 6;
    int c = (t < NBUK) ? bcnt[t] : 0;
    int v = c;
    for (int d = 1; d < 64; d <<= 1) { int n = __shfl_up(v, d); if (lane >= d) v += n; }
    if (lane == 63) wsum[w] = v;
    __syncthreads();
    int pre = 0;
    for (int q = 0; q < w; ++q) pre += wsum[q];
    int excl = pre + v - c;
    if (t <= NBUK) {
        bbase[t] = excl;
        if (t < NBUK) gcur[t] = excl;
    }
    if (t == 0) offs[NN] = EE;
}

// scatter packed (src<<8)|(dst&255) into CSR-ordered bucket regions
__global__ __launch_bounds__(256) void k_p1(const int* __restrict__ ei,
                                            int* __restrict__ gcur,
                                            unsigned int* __restrict__ pairs) {
    __shared__ int h[NBUK];
    int t = threadIdx.x;
    for (int i = t; i < NBUK; i += 256) h[i] = 0;
    __syncthreads();
    const int4* src4 = (const int4*)ei;
    const int4* dst4 = (const int4*)(ei + EE);
    int base4 = blockIdx.x * 4096;
    for (int j = 0; j < 16; ++j) {
        int i4 = base4 + j * 256 + t;
        if (i4 < EE / 4) {
            int4 d = dst4[i4];
            atomicAdd(&h[d.x >> 8], 1);
            atomicAdd(&h[d.y >> 8], 1);
            atomicAdd(&h[d.z >> 8], 1);
            atomicAdd(&h[d.w >> 8], 1);
        }
    }
    __syncthreads();
    // reserve contiguous global runs; h becomes global write cursor
    for (int i = t; i < NBUK; i += 256) {
        int c = h[i];
        h[i] = c ? atomicAdd(&gcur[i], c) : 0;
    }
    __syncthreads();
    for (int j = 0; j < 16; ++j) {
        int i4 = base4 + j * 256 + t;
        if (i4 < EE / 4) {
            int4 d = dst4[i4];
            int4 s = src4[i4];
            int p0 = atomicAdd(&h[d.x >> 8], 1);
            pairs[p0] = ((unsigned int)s.x << 8) | (unsigned int)(d.x & 255);
            int p1 = atomicAdd(&h[d.y >> 8], 1);
            pairs[p1] = ((unsigned int)s.y << 8) | (unsigned int)(d.y & 255);
            int p2 = atomicAdd(&h[d.z >> 8], 1);
            pairs[p2] = ((unsigned int)s.z << 8) | (unsigned int)(d.z & 255);
            int p3 = atomicAdd(&h[d.w >> 8], 1);
            pairs[p3] = ((unsigned int)s.w << 8) | (unsigned int)(d.w & 255);
        }
    }
}

// per-bucket (256 nodes) CSR finalize in LDS: count, scan, scatter col
__global__ __launch_bounds__(256) void k_p2(const unsigned int* __restrict__ pairs,
                                            const int* __restrict__ bbase,
                                            int* __restrict__ offs, float* __restrict__ dinv,
                                            int* __restrict__ col) {
    int b = blockIdx.x, t = threadIdx.x;
    int nbase = b << 8;
    int ebase = bbase[b], eend = bbase[b + 1];
    int m = eend - ebase;
    __shared__ int cnt[256];
    __shared__ int wsum[4];
    cnt[t] = 0;
    __syncthreads();
    for (int i = t; i < m; i += 256)
        atomicAdd(&cnt[pairs[ebase + i] & 255u], 1);
    __syncthreads();
    int c = cnt[t];
    int lane = t & 63, w = t >> 6;
    int v = c;
    for (int d = 1; d < 64; d <<= 1) { int n = __shfl_up(v, d); if (lane >= d) v += n; }
    if (lane == 63) wsum[w] = v;
    __syncthreads();
    int pre = 0;
    for (int q = 0; q < w; ++q) pre += wsum[q];
    int excl = pre + v - c;
    int node = nbase + t;
    if (node < NN) {
        offs[node] = ebase + excl;
        dinv[node] = rsqrtf(1.f + (float)c);
    }
    __syncthreads();
    cnt[t] = excl;  // reuse as local cursor
    __syncthreads();
    for (int i = t; i < m; i += 256) {
        unsigned int u = pairs[ebase + i];
        int loc = atomicAdd(&cnt[u & 255u], 1);
        col[ebase + loc] = (int)(u >> 8);
    }
}

// ---------------- BN constant folding ----------------
__global__ void k_precompute_bn(const float* b1, const float* g1, const float* be1,
                                const float* rm1, const float* rv1,
                                const float* b2, const float* g2, const float* be2,
                                const float* rm2, const float* rv2, float* sc) {
    int l = threadIdx.x;
    float s1 = g1[l] * rsqrtf(rv1[l] + EPS);
    sc[l]       = s1;
    sc[64 + l]  = (b1[l] - rm1[l]) * s1 + be1[l];
    float s2 = g2[l] * rsqrtf(rv2[l] + EPS);
    sc[128 + l] = s2;
    sc[192 + l] = (b2[l] - rm2[l]) * s2 + be2[l];
}

// ---------------- GEMM: [nrows, K] @ [K, 64], LDS-staged X ----------------
// kb loop kept rolled: full unroll -> 256 VGPR + scratch spill (R2).
template <int K>
__global__ __launch_bounds__(256) void k_gemm_lds(const float* __restrict__ X,
                                                  const float* __restrict__ W,
                                                  float* __restrict__ out, int nrows) {
    __shared__ float Wl[K * 64];
    __shared__ float Xl[64 * K];
    int tid = threadIdx.x;
    for (int i = tid * 4; i < K * 64; i += 1024)
        *(float4*)&Wl[i] = *(const float4*)&W[i];
    int r0 = blockIdx.x * 64;
    const float* Xbase = X + (size_t)r0 * K;
    int limit = (nrows - r0) * K;
    for (int i = tid * 4; i < 64 * K; i += 1024) {
        float4 v = {0.f, 0.f, 0.f, 0.f};
        if (i + 3 < limit) v = *(const float4*)&Xbase[i];
        *(float4*)&Xl[i] = v;
    }
    __syncthreads();
    int lane = tid & 63, wv = tid >> 6;
    const float* xbase = &Xl[wv * 16 * K];
    float acc[16];
#pragma unroll
    for (int r = 0; r < 16; ++r) acc[r] = 0.f;
#pragma unroll 1
    for (int kb = 0; kb < K; kb += 4) {
        float w0 = Wl[(kb + 0) * 64 + lane];
        float w1 = Wl[(kb + 1) * 64 + lane];
        float w2 = Wl[(kb + 2) * 64 + lane];
        float w3 = Wl[(kb + 3) * 64 + lane];
#pragma unroll
        for (int r = 0; r < 16; ++r) {
            float4 xv = *(const float4*)&xbase[r * K + kb];
            float a = acc[r];
            a = fmaf(xv.x, w0, a);
            a = fmaf(xv.y, w1, a);
            a = fmaf(xv.z, w2, a);
            a = fmaf(xv.w, w3, a);
            acc[r] = a;
        }
    }
    int gr = r0 + wv * 16;
#pragma unroll
    for (int r = 0; r < 16; ++r)
        if (gr + r < nrows) out[(size_t)(gr + r) * 64 + lane] = acc[r];
}

// ---------------- fused GCN aggregate + selfloop + BN + ReLU (+resid) ------
__global__ void k_gcn_gather(const float* __restrict__ hw, const int* __restrict__ col,
                             const int* __restrict__ offs,
                             const float* __restrict__ dinv, const float* __restrict__ scale,
                             const float* __restrict__ shift, const float* __restrict__ resid,
                             float* __restrict__ out) {
    int node = blockIdx.x * 4 + (threadIdx.x >> 6);
    if (node >= NN) return;
    int lane = threadIdx.x & 63;
    int e0 = offs[node], e1 = offs[node + 1];
    float di = dinv[node];
    float a0 = 0.f, a1 = 0.f, a2 = 0.f, a3 = 0.f;
    for (int base = e0; base < e1; base += 64) {
        int m = e1 - base; if (m > 64) m = 64;
        int srcv = 0; float wv = 0.f;
        if (lane < m) { srcv = col[base + lane]; wv = dinv[srcv]; }
        int j = 0;
        for (; j + 4 <= m; j += 4) {
            int s0 = __shfl(srcv, j), s1 = __shfl(srcv, j + 1);
            int s2 = __shfl(srcv, j + 2), s3 = __shfl(srcv, j + 3);
            float n0 = __shfl(wv, j), n1 = __shfl(wv, j + 1);
            float n2 = __shfl(wv, j + 2), n3 = __shfl(wv, j + 3);
            float v0 = hw[s0 * 64 + lane];
            float v1 = hw[s1 * 64 + lane];
            float v2 = hw[s2 * 64 + lane];
            float v3 = hw[s3 * 64 + lane];
            a0 = fmaf(v0, n0, a0); a1 = fmaf(v1, n1, a1);
            a2 = fmaf(v2, n2, a2); a3 = fmaf(v3, n3, a3);
        }
        for (; j < m; ++j) {
            int s = __shfl(srcv, j); float n = __shfl(wv, j);
            a0 = fmaf(hw[s * 64 + lane], n, a0);
        }
    }
    float acc = ((a0 + a1) + (a2 + a3)) * di;
    float v = acc + hw[(long)node * 64 + lane] * di * di;
    v = fmaf(v, scale[lane], shift[lane]);
    v = fmaxf(v, 0.f);
    if (resid) v += resid[(long)node * 64 + lane];
    out[(long)node * 64 + lane] = v;
}

// ---------------- pooling over sorted batch ----------------
__global__ void k_pool(const float* __restrict__ h, const int* __restrict__ batch,
                       float* __restrict__ msum, float* __restrict__ mmax,
                       float* __restrict__ gcnt) {
    int lane = threadIdx.x;  // 64
    int i0 = blockIdx.x * 128;
    int i1 = i0 + 128; if (i1 > NN) i1 = NN;
    int cur = batch[i0];
    float sum = 0.f, mx = 0.f; int c = 0;
    for (int i = i0; i < i1; ++i) {
        int g = batch[i];
        if (g != cur) {
            atomicAdd(&msum[cur * 64 + lane], sum);
            atomicMax((unsigned int*)&mmax[cur * 64 + lane], __float_as_uint(mx));
            if (lane == 0) atomicAdd(&gcnt[cur], (float)c);
            sum = 0.f; mx = 0.f; c = 0; cur = g;
        }
        float v = h[(long)i * 64 + lane];
        sum += v; mx = fmaxf(mx, v); ++c;
    }
    atomicAdd(&msum[cur * 64 + lane], sum);
    atomicMax((unsigned int*)&mmax[cur * 64 + lane], __float_as_uint(mx));
    if (lane == 0) atomicAdd(&gcnt[cur], (float)c);
}

// ---------------- MLP head, one block per graph ----------------
__global__ void k_head(const float* __restrict__ msum, const float* __restrict__ mmax,
                       const float* __restrict__ gcnt,
                       const float* __restrict__ Wh1, const float* __restrict__ bh1,
                       const float* __restrict__ Wh2, const float* __restrict__ bh2,
                       const float* __restrict__ Wh3, const float* __restrict__ bh3,
                       float* __restrict__ out) {
    int g = blockIdx.x, t = threadIdx.x;  // 64 threads
    __shared__ float hg[128];
    __shared__ float z1[64];
    __shared__ float z2[32];
    float c = fmaxf(gcnt[g], 1.f);
    hg[t]      = msum[g * 64 + t] / c;
    hg[64 + t] = mmax[g * 64 + t];
    __syncthreads();
    float acc = bh1[t];
#pragma unroll 8
    for (int k = 0; k < 128; ++k) acc = fmaf(hg[k], Wh1[k * 64 + t], acc);
    z1[t] = fmaxf(acc, 0.f);
    __syncthreads();
    if (t < 32) {
        float a2 = bh2[t];
#pragma unroll 8
        for (int k = 0; k < 64; ++k) a2 = fmaf(z1[k], Wh2[k * 32 + t], a2);
        z2[t] = fmaxf(a2, 0.f);
    }
    __syncthreads();
    if (t == 0) {
        float a3 = bh3[0];
        for (int k = 0; k < 32; ++k) a3 = fmaf(z2[k], Wh3[k], a3);
        out[g] = 1.f / (1.f + expf(-a3));
    }
}

// ---------------- launcher ----------------

static inline size_t alignup(size_t x) { return (x + 255) & ~(size_t)255; }

extern "C" void kernel_launch(void* const* d_in, const int* in_sizes, int n_in,
                              void* d_out, int out_size, void* d_ws, size_t ws_size,
                              hipStream_t stream) {
    const float* x   = (const float*)d_in[0];
    const int*   ei  = (const int*)d_in[1];
    const int*   bat = (const int*)d_in[2];
    const float* W1  = (const float*)d_in[3];
    const float* b1  = (const float*)d_in[4];
    const float* g1  = (const float*)d_in[5];
    const float* be1 = (const float*)d_in[6];
    const float* rm1 = (const float*)d_in[7];
    const float* rv1 = (const float*)d_in[8];
    const float* W2  = (const float*)d_in[9];
    const float* b2  = (const float*)d_in[10];
    const float* g2  = (const float*)d_in[11];
    const float* be2 = (const float*)d_in[12];
    const float* rm2 = (const float*)d_in[13];
    const float* rv2 = (const float*)d_in[14];
    const float* Wh1 = (const float*)d_in[15];
    const float* bh1 = (const float*)d_in[16];
    const float* Wh2 = (const float*)d_in[17];
    const float* bh2 = (const float*)d_in[18];
    const float* Wh3 = (const float*)d_in[19];
    const float* bh3 = (const float*)d_in[20];
    float* out = (float*)d_out;

    char* ws = (char*)d_ws;
    size_t o = 0;
    int*   bcnt   = (int*)(ws + o);  o = alignup(o + NBUK * 4);
    int*   bbase  = (int*)(ws + o);  o = alignup(o + (NBUK + 1) * 4);
    int*   gcur   = (int*)(ws + o);  o = alignup(o + NBUK * 4);
    int*   offs   = (int*)(ws + o);  o = alignup(o + (NN + 1) * 4);
    unsigned int* pairs = (unsigned int*)(ws + o); o = alignup(o + (size_t)EE * 4);
    int*   col    = (int*)(ws + o);  o = alignup(o + (size_t)EE * 4);
    float* dinv   = (float*)(ws + o); o = alignup(o + (size_t)NN * 4);
    float* scb    = (float*)(ws + o); o = alignup(o + 4 * 64 * 4);
    float* msum   = (float*)(ws + o);
    size_t pool_off = o;              o += (size_t)GG * 64 * 4;
    float* mmax   = (float*)(ws + o); o += (size_t)GG * 64 * 4;
    float* gcnt   = (float*)(ws + o); o += (size_t)GG * 4;
    size_t pool_bytes = o - pool_off; o = alignup(o);
    float* hw     = (float*)(ws + o); o = alignup(o + (size_t)NN * 64 * 4);
    float* h      = (float*)(ws + o); o = alignup(o + (size_t)NN * 64 * 4);
    (void)ws_size; (void)n_in; (void)in_sizes; (void)out_size;

    hipMemsetAsync(bcnt, 0, NBUK * 4, stream);
    hipMemsetAsync(ws + pool_off, 0, pool_bytes, stream);

    k_precompute_bn<<<1, 64, 0, stream>>>(b1, g1, be1, rm1, rv1, b2, g2, be2, rm2, rv2, scb);
    k_bhist<<<P1_TILES, 256, 0, stream>>>(ei, bcnt);
    k_bscan<<<1, 512, 0, stream>>>(bcnt, bbase, gcur, offs);
    k_p1<<<P1_TILES, 256, 0, stream>>>(ei, gcur, pairs);
    k_p2<<<NBUK, 256, 0, stream>>>(pairs, bbase, offs, dinv, col);

    // layer 1
    k_gemm_lds<INF_><<<(NN + 63) / 64, 256, 0, stream>>>(x, W1, hw, NN);
    k_gcn_gather<<<(NN + 3) / 4, 256, 0, stream>>>(hw, col, offs, dinv,
                                                   scb, scb + 64, nullptr, h);
    // layer 2 (residual, in-place into h)
    k_gemm_lds<HID><<<(NN + 63) / 64, 256, 0, stream>>>(h, W2, hw, NN);
    k_gcn_gather<<<(NN + 3) / 4, 256, 0, stream>>>(hw, col, offs, dinv,
                                                   scb + 128, scb + 192, h, h);
    // pooling + head
    k_pool<<<(NN + 127) / 128, 64, 0, stream>>>(h, bat, msum, mmax, gcnt);
    k_head<<<GG, 64, 0, stream>>>(msum, mmax, gcnt, Wh1, bh1, Wh2, bh2, Wh3, bh3, out);
}

// Round 5
// 408.311 us; speedup vs baseline: 2.1924x; 1.0680x over previous
//
#include <hip/hip_runtime.h>
#include <math.h>

#define NN 100000
#define EE 1600000
#define GG 512
#define INF_ 128
#define HID 64
#define EPS 1e-5f

#define NBUK 391          // ceil(NN/256), bucket = dst >> 8
#define P1_TILES 98       // ceil((EE/4)/4096)

typedef unsigned int uint32;

// bf16 helpers: RNE pack, shift decode
static __device__ inline uint32 f2bf(float f) {
    uint32 u = __float_as_uint(f);
    return (u + 0x7FFFu + ((u >> 16) & 1u)) >> 16;
}
static __device__ inline float bf_lo(uint32 u) { return __uint_as_float(u << 16); }
static __device__ inline float bf_hi(uint32 u) { return __uint_as_float(u & 0xFFFF0000u); }

// ---------------- CSR build: 2-level counting sort ----------------
// R3: per-edge atomic scatter had 12x write amplification from cross-XCD
// line bouncing. Block-aggregated bucket sort keeps lines block-owned.

__global__ __launch_bounds__(256) void k_bhist(const int* __restrict__ ei,
                                               int* __restrict__ bcnt) {
    __shared__ int h[NBUK];
    int t = threadIdx.x;
    for (int i = t; i < NBUK; i += 256) h[i] = 0;
    __syncthreads();
    const int4* dst4 = (const int4*)(ei + EE);
    int base4 = blockIdx.x * 4096;
    for (int j = 0; j < 16; ++j) {
        int i4 = base4 + j * 256 + t;
        if (i4 < EE / 4) {
            int4 d = dst4[i4];
            atomicAdd(&h[d.x >> 8], 1);
            atomicAdd(&h[d.y >> 8], 1);
            atomicAdd(&h[d.z >> 8], 1);
            atomicAdd(&h[d.w >> 8], 1);
        }
    }
    __syncthreads();
    for (int i = t; i < NBUK; i += 256)
        if (h[i]) atomicAdd(&bcnt[i], h[i]);
}

__global__ void k_bscan(const int* __restrict__ bcnt, int* __restrict__ bbase,
                        int* __restrict__ gcur, int* __restrict__ offs) {
    __shared__ int wsum[8];
    int t = threadIdx.x;  // 512
    int lane = t & 63, w = t >> 6;
    int c = (t < NBUK) ? bcnt[t] : 0;
    int v = c;
    for (int d = 1; d < 64; d <<= 1) { int n = __shfl_up(v, d); if (lane >= d) v += n; }
    if (lane == 63) wsum[w] = v;
    __syncthreads();
    int pre = 0;
    for (int q = 0; q < w; ++q) pre += wsum[q];
    int excl = pre + v - c;
    if (t <= NBUK) {
        bbase[t] = excl;
        if (t < NBUK) gcur[t] = excl;
    }
    if (t == 0) offs[NN] = EE;
}

// scatter packed (src<<8)|(dst&255) into CSR-ordered bucket regions
__global__ __launch_bounds__(256) void k_p1(const int* __restrict__ ei,
                                            int* __restrict__ gcur,
                                            uint32* __restrict__ pairs) {
    __shared__ int h[NBUK];
    int t = threadIdx.x;
    for (int i = t; i < NBUK; i += 256) h[i] = 0;
    __syncthreads();
    const int4* src4 = (const int4*)ei;
    const int4* dst4 = (const int4*)(ei + EE);
    int base4 = blockIdx.x * 4096;
    for (int j = 0; j < 16; ++j) {
        int i4 = base4 + j * 256 + t;
        if (i4 < EE / 4) {
            int4 d = dst4[i4];
            atomicAdd(&h[d.x >> 8], 1);
            atomicAdd(&h[d.y >> 8], 1);
            atomicAdd(&h[d.z >> 8], 1);
            atomicAdd(&h[d.w >> 8], 1);
        }
    }
    __syncthreads();
    for (int i = t; i < NBUK; i += 256) {
        int c = h[i];
        h[i] = c ? atomicAdd(&gcur[i], c) : 0;
    }
    __syncthreads();
    for (int j = 0; j < 16; ++j) {
        int i4 = base4 + j * 256 + t;
        if (i4 < EE / 4) {
            int4 d = dst4[i4];
            int4 s = src4[i4];
            int p0 = atomicAdd(&h[d.x >> 8], 1);
            pairs[p0] = ((uint32)s.x << 8) | (uint32)(d.x & 255);
            int p1 = atomicAdd(&h[d.y >> 8], 1);
            pairs[p1] = ((uint32)s.y << 8) | (uint32)(d.y & 255);
            int p2 = atomicAdd(&h[d.z >> 8], 1);
            pairs[p2] = ((uint32)s.z << 8) | (uint32)(d.z & 255);
            int p3 = atomicAdd(&h[d.w >> 8], 1);
            pairs[p3] = ((uint32)s.w << 8) | (uint32)(d.w & 255);
        }
    }
}

// per-bucket (256 nodes) CSR finalize in LDS: count, scan, scatter col
__global__ __launch_bounds__(256) void k_p2(const uint32* __restrict__ pairs,
                                            const int* __restrict__ bbase,
                                            int* __restrict__ offs, float* __restrict__ dinv,
                                            int* __restrict__ col) {
    int b = blockIdx.x, t = threadIdx.x;
    int nbase = b << 8;
    int ebase = bbase[b], eend = bbase[b + 1];
    int m = eend - ebase;
    __shared__ int cnt[256];
    __shared__ int wsum[4];
    cnt[t] = 0;
    __syncthreads();
    for (int i = t; i < m; i += 256)
        atomicAdd(&cnt[pairs[ebase + i] & 255u], 1);
    __syncthreads();
    int c = cnt[t];
    int lane = t & 63, w = t >> 6;
    int v = c;
    for (int d = 1; d < 64; d <<= 1) { int n = __shfl_up(v, d); if (lane >= d) v += n; }
    if (lane == 63) wsum[w] = v;
    __syncthreads();
    int pre = 0;
    for (int q = 0; q < w; ++q) pre += wsum[q];
    int excl = pre + v - c;
    int node = nbase + t;
    if (node < NN) {
        offs[node] = ebase + excl;
        dinv[node] = rsqrtf(1.f + (float)c);
    }
    __syncthreads();
    cnt[t] = excl;
    __syncthreads();
    for (int i = t; i < m; i += 256) {
        uint32 u = pairs[ebase + i];
        int loc = atomicAdd(&cnt[u & 255u], 1);
        col[ebase + loc] = (int)(u >> 8);
    }
}

// ---------------- BN constant folding ----------------
__global__ void k_precompute_bn(const float* b1, const float* g1, const float* be1,
                                const float* rm1, const float* rv1,
                                const float* b2, const float* g2, const float* be2,
                                const float* rm2, const float* rv2, float* sc) {
    int l = threadIdx.x;
    float s1 = g1[l] * rsqrtf(rv1[l] + EPS);
    sc[l]       = s1;
    sc[64 + l]  = (b1[l] - rm1[l]) * s1 + be1[l];
    float s2 = g2[l] * rsqrtf(rv2[l] + EPS);
    sc[128 + l] = s2;
    sc[192 + l] = (b2[l] - rm2[l]) * s2 + be2[l];
}

// ---------------- GEMM: [nrows, K] @ [K, 64] -> bf16-packed out ----------
// kb loop kept rolled: full unroll -> 256 VGPR + scratch spill (R2).
// Output packed 2xbf16/uint, [nrows][32]: gather reads half the bytes.
template <int K>
__global__ __launch_bounds__(256) void k_gemm_lds(const float* __restrict__ X,
                                                  const float* __restrict__ W,
                                                  uint32* __restrict__ outb, int nrows) {
    __shared__ float Wl[K * 64];
    __shared__ float Xl[64 * K];
    int tid = threadIdx.x;
    for (int i = tid * 4; i < K * 64; i += 1024)
        *(float4*)&Wl[i] = *(const float4*)&W[i];
    int r0 = blockIdx.x * 64;
    const float* Xbase = X + (size_t)r0 * K;
    int limit = (nrows - r0) * K;
    for (int i = tid * 4; i < 64 * K; i += 1024) {
        float4 v = {0.f, 0.f, 0.f, 0.f};
        if (i + 3 < limit) v = *(const float4*)&Xbase[i];
        *(float4*)&Xl[i] = v;
    }
    __syncthreads();
    int lane = tid & 63, wv = tid >> 6;
    const float* xbase = &Xl[wv * 16 * K];
    float acc[16];
#pragma unroll
    for (int r = 0; r < 16; ++r) acc[r] = 0.f;
#pragma unroll 1
    for (int kb = 0; kb < K; kb += 4) {
        float w0 = Wl[(kb + 0) * 64 + lane];
        float w1 = Wl[(kb + 1) * 64 + lane];
        float w2 = Wl[(kb + 2) * 64 + lane];
        float w3 = Wl[(kb + 3) * 64 + lane];
#pragma unroll
        for (int r = 0; r < 16; ++r) {
            float4 xv = *(const float4*)&xbase[r * K + kb];
            float a = acc[r];
            a = fmaf(xv.x, w0, a);
            a = fmaf(xv.y, w1, a);
            a = fmaf(xv.z, w2, a);
            a = fmaf(xv.w, w3, a);
            acc[r] = a;
        }
    }
    int gr = r0 + wv * 16;
#pragma unroll
    for (int r = 0; r < 16; ++r) {
        float nxt = __shfl_down(acc[r], 1);     // even lane l: features l, l+1
        if (((lane & 1) == 0) && (gr + r < nrows))
            outb[(size_t)(gr + r) * 32 + (lane >> 1)] = f2bf(acc[r]) | (f2bf(nxt) << 16);
    }
}

// ---------- fused GCN aggregate + selfloop + BN + ReLU (+resid), bf16 ------
// One wave per node. 32 lanes cover a 128B bf16 row (2 features/lane);
// the two wave halves process 2 edges per load (per-lane shfl index j+half).
// Lanes >= m have wv=0, so odd tails contribute nothing automatically.
__global__ void k_gcn_gather(const uint32* __restrict__ hwb, const int* __restrict__ col,
                             const int* __restrict__ offs,
                             const float* __restrict__ dinv, const float* __restrict__ scale,
                             const float* __restrict__ shift, const float* __restrict__ resid,
                             float* __restrict__ out) {
    int node = blockIdx.x * 4 + (threadIdx.x >> 6);
    if (node >= NN) return;
    int lane = threadIdx.x & 63;
    int half = lane >> 5;
    int fl = lane & 31;                 // feature pair: {2fl, 2fl+1}
    int e0 = offs[node], e1 = offs[node + 1];
    float di = dinv[node];
    float ax = 0.f, ay = 0.f;
    for (int base = e0; base < e1; base += 64) {
        int m = e1 - base; if (m > 64) m = 64;
        int srcv = 0; float wv = 0.f;
        if (lane < m) { srcv = col[base + lane]; wv = dinv[srcv]; }
        int j = 0;
        for (; j + 4 <= m; j += 4) {
            int   sa = __shfl(srcv, j + half);
            int   sb = __shfl(srcv, j + 2 + half);
            float na = __shfl(wv, j + half);
            float nb = __shfl(wv, j + 2 + half);
            uint32 ua = hwb[(size_t)sa * 32 + fl];
            uint32 ub = hwb[(size_t)sb * 32 + fl];
            ax = fmaf(bf_lo(ua), na, ax); ay = fmaf(bf_hi(ua), na, ay);
            ax = fmaf(bf_lo(ub), nb, ax); ay = fmaf(bf_hi(ub), nb, ay);
        }
        for (; j < m; j += 2) {
            int   s = __shfl(srcv, j + half);
            float n = __shfl(wv, j + half);
            uint32 u = hwb[(size_t)s * 32 + fl];
            ax = fmaf(bf_lo(u), n, ax); ay = fmaf(bf_hi(u), n, ay);
        }
    }
    // combine the two halves: lane<32 pulls partner lane+32
    ax += __shfl(ax, fl + 32);
    ay += __shfl(ay, fl + 32);
    if (half == 0) {
        uint32 uself = hwb[(size_t)node * 32 + fl];
        float dii = di * di;
        float vx = fmaf(ax * di + bf_lo(uself) * dii, scale[2 * fl],     shift[2 * fl]);
        float vy = fmaf(ay * di + bf_hi(uself) * dii, scale[2 * fl + 1], shift[2 * fl + 1]);
        vx = fmaxf(vx, 0.f);
        vy = fmaxf(vy, 0.f);
        if (resid) {
            float2 rv = *(const float2*)&resid[(size_t)node * 64 + 2 * fl];
            vx += rv.x; vy += rv.y;
        }
        float2 o; o.x = vx; o.y = vy;
        *(float2*)&out[(size_t)node * 64 + 2 * fl] = o;
    }
}

// ---------------- pooling over sorted batch ----------------
__global__ void k_pool(const float* __restrict__ h, const int* __restrict__ batch,
                       float* __restrict__ msum, float* __restrict__ mmax,
                       float* __restrict__ gcnt) {
    int lane = threadIdx.x;  // 64
    int i0 = blockIdx.x * 128;
    int i1 = i0 + 128; if (i1 > NN) i1 = NN;
    int cur = batch[i0];
    float sum = 0.f, mx = 0.f; int c = 0;
    for (int i = i0; i < i1; ++i) {
        int g = batch[i];
        if (g != cur) {
            atomicAdd(&msum[cur * 64 + lane], sum);
            atomicMax((unsigned int*)&mmax[cur * 64 + lane], __float_as_uint(mx));
            if (lane == 0) atomicAdd(&gcnt[cur], (float)c);
            sum = 0.f; mx = 0.f; c = 0; cur = g;
        }
        float v = h[(long)i * 64 + lane];
        sum += v; mx = fmaxf(mx, v); ++c;
    }
    atomicAdd(&msum[cur * 64 + lane], sum);
    atomicMax((unsigned int*)&mmax[cur * 64 + lane], __float_as_uint(mx));
    if (lane == 0) atomicAdd(&gcnt[cur], (float)c);
}

// ---------------- MLP head, one block per graph ----------------
__global__ void k_head(const float* __restrict__ msum, const float* __restrict__ mmax,
                       const float* __restrict__ gcnt,
                       const float* __restrict__ Wh1, const float* __restrict__ bh1,
                       const float* __restrict__ Wh2, const float* __restrict__ bh2,
                       const float* __restrict__ Wh3, const float* __restrict__ bh3,
                       float* __restrict__ out) {
    int g = blockIdx.x, t = threadIdx.x;  // 64 threads
    __shared__ float hg[128];
    __shared__ float z1[64];
    __shared__ float z2[32];
    float c = fmaxf(gcnt[g], 1.f);
    hg[t]      = msum[g * 64 + t] / c;
    hg[64 + t] = mmax[g * 64 + t];
    __syncthreads();
    float acc = bh1[t];
#pragma unroll 8
    for (int k = 0; k < 128; ++k) acc = fmaf(hg[k], Wh1[k * 64 + t], acc);
    z1[t] = fmaxf(acc, 0.f);
    __syncthreads();
    if (t < 32) {
        float a2 = bh2[t];
#pragma unroll 8
        for (int k = 0; k < 64; ++k) a2 = fmaf(z1[k], Wh2[k * 32 + t], a2);
        z2[t] = fmaxf(a2, 0.f);
    }
    __syncthreads();
    if (t == 0) {
        float a3 = bh3[0];
        for (int k = 0; k < 32; ++k) a3 = fmaf(z2[k], Wh3[k], a3);
        out[g] = 1.f / (1.f + expf(-a3));
    }
}

// ---------------- launcher ----------------

static inline size_t alignup(size_t x) { return (x + 255) & ~(size_t)255; }

extern "C" void kernel_launch(void* const* d_in, const int* in_sizes, int n_in,
                              void* d_out, int out_size, void* d_ws, size_t ws_size,
                              hipStream_t stream) {
    const float* x   = (const float*)d_in[0];
    const int*   ei  = (const int*)d_in[1];
    const int*   bat = (const int*)d_in[2];
    const float* W1  = (const float*)d_in[3];
    const float* b1  = (const float*)d_in[4];
    const float* g1  = (const float*)d_in[5];
    const float* be1 = (const float*)d_in[6];
    const float* rm1 = (const float*)d_in[7];
    const float* rv1 = (const float*)d_in[8];
    const float* W2  = (const float*)d_in[9];
    const float* b2  = (const float*)d_in[10];
    const float* g2  = (const float*)d_in[11];
    const float* be2 = (const float*)d_in[12];
    const float* rm2 = (const float*)d_in[13];
    const float* rv2 = (const float*)d_in[14];
    const float* Wh1 = (const float*)d_in[15];
    const float* bh1 = (const float*)d_in[16];
    const float* Wh2 = (const float*)d_in[17];
    const float* bh2 = (const float*)d_in[18];
    const float* Wh3 = (const float*)d_in[19];
    const float* bh3 = (const float*)d_in[20];
    float* out = (float*)d_out;

    char* ws = (char*)d_ws;
    size_t o = 0;
    int*   bcnt   = (int*)(ws + o);  o = alignup(o + NBUK * 4);
    int*   bbase  = (int*)(ws + o);  o = alignup(o + (NBUK + 1) * 4);
    int*   gcur   = (int*)(ws + o);  o = alignup(o + NBUK * 4);
    int*   offs   = (int*)(ws + o);  o = alignup(o + (NN + 1) * 4);
    uint32* pairs = (uint32*)(ws + o); o = alignup(o + (size_t)EE * 4);
    int*   col    = (int*)(ws + o);  o = alignup(o + (size_t)EE * 4);
    float* dinv   = (float*)(ws + o); o = alignup(o + (size_t)NN * 4);
    float* scb    = (float*)(ws + o); o = alignup(o + 4 * 64 * 4);
    float* msum   = (float*)(ws + o);
    size_t pool_off = o;              o += (size_t)GG * 64 * 4;
    float* mmax   = (float*)(ws + o); o += (size_t)GG * 64 * 4;
    float* gcnt   = (float*)(ws + o); o += (size_t)GG * 4;
    size_t pool_bytes = o - pool_off; o = alignup(o);
    uint32* hwb   = (uint32*)(ws + o); o = alignup(o + (size_t)NN * 32 * 4);
    float* h      = (float*)(ws + o); o = alignup(o + (size_t)NN * 64 * 4);
    (void)ws_size; (void)n_in; (void)in_sizes; (void)out_size;

    hipMemsetAsync(bcnt, 0, NBUK * 4, stream);
    hipMemsetAsync(ws + pool_off, 0, pool_bytes, stream);

    k_precompute_bn<<<1, 64, 0, stream>>>(b1, g1, be1, rm1, rv1, b2, g2, be2, rm2, rv2, scb);
    k_bhist<<<P1_TILES, 256, 0, stream>>>(ei, bcnt);
    k_bscan<<<1, 512, 0, stream>>>(bcnt, bbase, gcur, offs);
    k_p1<<<P1_TILES, 256, 0, stream>>>(ei, gcur, pairs);
    k_p2<<<NBUK, 256, 0, stream>>>(pairs, bbase, offs, dinv, col);

    // layer 1
    k_gemm_lds<INF_><<<(NN + 63) / 64, 256, 0, stream>>>(x, W1, hwb, NN);
    k_gcn_gather<<<(NN + 3) / 4, 256, 0, stream>>>(hwb, col, offs, dinv,
                                                   scb, scb + 64, nullptr, h);
    // layer 2 (residual, in-place into h)
    k_gemm_lds<HID><<<(NN + 63) / 64, 256, 0, stream>>>(h, W2, hwb, NN);
    k_gcn_gather<<<(NN + 3) / 4, 256, 0, stream>>>(hwb, col, offs, dinv,
                                                   scb + 128, scb + 192, h, h);
    // pooling + head
    k_pool<<<(NN + 127) / 128, 64, 0, stream>>>(h, bat, msum, mmax, gcnt);
    k_head<<<GG, 64, 0, stream>>>(msum, mmax, gcnt, Wh1, bh1, Wh2, bh2, Wh3, bh3, out);
}

// Round 6
// 357.502 us; speedup vs baseline: 2.5040x; 1.1421x over previous
//
#include <hip/hip_runtime.h>
#include <math.h>

#define NN 100000
#define EE 1600000
#define GG 512
#define INF_ 128
#define HID 64
#define EPS 1e-5f

#define NBUK 391          // ceil(NN/256), bucket = dst >> 8
#define P1_TILES 98       // ceil((EE/4)/4096)

typedef unsigned int uint32;
typedef __attribute__((ext_vector_type(8))) short bf16x8;
typedef __attribute__((ext_vector_type(4))) float f32x4;

// bf16 helpers: RNE pack, shift decode
static __device__ inline uint32 f2bf(float f) {
    uint32 u = __float_as_uint(f);
    return (u + 0x7FFFu + ((u >> 16) & 1u)) >> 16;
}
static __device__ inline float bf_lo(uint32 u) { return __uint_as_float(u << 16); }
static __device__ inline float bf_hi(uint32 u) { return __uint_as_float(u & 0xFFFF0000u); }

// ---------------- CSR build: 2-level counting sort ----------------
// R3: per-edge atomic scatter had 12x write amplification from cross-XCD
// line bouncing. Block-aggregated bucket sort keeps lines block-owned.

__global__ __launch_bounds__(256) void k_bhist(const int* __restrict__ ei,
                                               int* __restrict__ bcnt) {
    __shared__ int h[NBUK];
    int t = threadIdx.x;
    for (int i = t; i < NBUK; i += 256) h[i] = 0;
    __syncthreads();
    const int4* dst4 = (const int4*)(ei + EE);
    int base4 = blockIdx.x * 4096;
    for (int j = 0; j < 16; ++j) {
        int i4 = base4 + j * 256 + t;
        if (i4 < EE / 4) {
            int4 d = dst4[i4];
            atomicAdd(&h[d.x >> 8], 1);
            atomicAdd(&h[d.y >> 8], 1);
            atomicAdd(&h[d.z >> 8], 1);
            atomicAdd(&h[d.w >> 8], 1);
        }
    }
    __syncthreads();
    for (int i = t; i < NBUK; i += 256)
        if (h[i]) atomicAdd(&bcnt[i], h[i]);
}

__global__ void k_bscan(const int* __restrict__ bcnt, int* __restrict__ bbase,
                        int* __restrict__ gcur, int* __restrict__ offs) {
    __shared__ int wsum[8];
    int t = threadIdx.x;  // 512
    int lane = t & 63, w = t >> 6;
    int c = (t < NBUK) ? bcnt[t] : 0;
    int v = c;
    for (int d = 1; d < 64; d <<= 1) { int n = __shfl_up(v, d); if (lane >= d) v += n; }
    if (lane == 63) wsum[w] = v;
    __syncthreads();
    int pre = 0;
    for (int q = 0; q < w; ++q) pre += wsum[q];
    int excl = pre + v - c;
    if (t <= NBUK) {
        bbase[t] = excl;
        if (t < NBUK) gcur[t] = excl;
    }
    if (t == 0) offs[NN] = EE;
}

// scatter packed (src<<8)|(dst&255) into CSR-ordered bucket regions
__global__ __launch_bounds__(256) void k_p1(const int* __restrict__ ei,
                                            int* __restrict__ gcur,
                                            uint32* __restrict__ pairs) {
    __shared__ int h[NBUK];
    int t = threadIdx.x;
    for (int i = t; i < NBUK; i += 256) h[i] = 0;
    __syncthreads();
    const int4* src4 = (const int4*)ei;
    const int4* dst4 = (const int4*)(ei + EE);
    int base4 = blockIdx.x * 4096;
    for (int j = 0; j < 16; ++j) {
        int i4 = base4 + j * 256 + t;
        if (i4 < EE / 4) {
            int4 d = dst4[i4];
            atomicAdd(&h[d.x >> 8], 1);
            atomicAdd(&h[d.y >> 8], 1);
            atomicAdd(&h[d.z >> 8], 1);
            atomicAdd(&h[d.w >> 8], 1);
        }
    }
    __syncthreads();
    for (int i = t; i < NBUK; i += 256) {
        int c = h[i];
        h[i] = c ? atomicAdd(&gcur[i], c) : 0;
    }
    __syncthreads();
    for (int j = 0; j < 16; ++j) {
        int i4 = base4 + j * 256 + t;
        if (i4 < EE / 4) {
            int4 d = dst4[i4];
            int4 s = src4[i4];
            int p0 = atomicAdd(&h[d.x >> 8], 1);
            pairs[p0] = ((uint32)s.x << 8) | (uint32)(d.x & 255);
            int p1 = atomicAdd(&h[d.y >> 8], 1);
            pairs[p1] = ((uint32)s.y << 8) | (uint32)(d.y & 255);
            int p2 = atomicAdd(&h[d.z >> 8], 1);
            pairs[p2] = ((uint32)s.z << 8) | (uint32)(d.z & 255);
            int p3 = atomicAdd(&h[d.w >> 8], 1);
            pairs[p3] = ((uint32)s.w << 8) | (uint32)(d.w & 255);
        }
    }
}

// per-bucket (256 nodes) CSR finalize in LDS: count, scan, scatter col
__global__ __launch_bounds__(256) void k_p2(const uint32* __restrict__ pairs,
                                            const int* __restrict__ bbase,
                                            int* __restrict__ offs, float* __restrict__ dinv,
                                            int* __restrict__ col) {
    int b = blockIdx.x, t = threadIdx.x;
    int nbase = b << 8;
    int ebase = bbase[b], eend = bbase[b + 1];
    int m = eend - ebase;
    __shared__ int cnt[256];
    __shared__ int wsum[4];
    cnt[t] = 0;
    __syncthreads();
    for (int i = t; i < m; i += 256)
        atomicAdd(&cnt[pairs[ebase + i] & 255u], 1);
    __syncthreads();
    int c = cnt[t];
    int lane = t & 63, w = t >> 6;
    int v = c;
    for (int d = 1; d < 64; d <<= 1) { int n = __shfl_up(v, d); if (lane >= d) v += n; }
    if (lane == 63) wsum[w] = v;
    __syncthreads();
    int pre = 0;
    for (int q = 0; q < w; ++q) pre += wsum[q];
    int excl = pre + v - c;
    int node = nbase + t;
    if (node < NN) {
        offs[node] = ebase + excl;
        dinv[node] = rsqrtf(1.f + (float)c);
    }
    __syncthreads();
    cnt[t] = excl;
    __syncthreads();
    for (int i = t; i < m; i += 256) {
        uint32 u = pairs[ebase + i];
        int loc = atomicAdd(&cnt[u & 255u], 1);
        col[ebase + loc] = (int)(u >> 8);
    }
}

// ---------------- BN constant folding ----------------
__global__ void k_precompute_bn(const float* b1, const float* g1, const float* be1,
                                const float* rm1, const float* rv1,
                                const float* b2, const float* g2, const float* be2,
                                const float* rm2, const float* rv2, float* sc) {
    int l = threadIdx.x;
    float s1 = g1[l] * rsqrtf(rv1[l] + EPS);
    sc[l]       = s1;
    sc[64 + l]  = (b1[l] - rm1[l]) * s1 + be1[l];
    float s2 = g2[l] * rsqrtf(rv2[l] + EPS);
    sc[128 + l] = s2;
    sc[192 + l] = (b2[l] - rm2[l]) * s2 + be2[l];
}

// ---------------- weight transpose+bf16: W[K][64] -> Wtb[64][K/2 uints] ----
__global__ void k_wt(const float* __restrict__ W, uint32* __restrict__ Wtb, int K) {
    int i = blockIdx.x * 256 + threadIdx.x;
    if (i >= 64 * K / 2) return;
    int n = i / (K / 2), kp = (i % (K / 2)) * 2;
    Wtb[i] = f2bf(W[(size_t)kp * 64 + n]) | (f2bf(W[(size_t)(kp + 1) * 64 + n]) << 16);
}

// ---------------- MFMA GEMM: [nrows,K]f32 @ [K,64]bf16 -> bf16 packed -----
// 64x64 tile/block, 4 waves; per wave: 4 n-tiles x K/32 k-steps of
// mfma_f32_16x16x32_bf16. X converted f32->bf16 during LDS staging.
// Rows padded +8 bf16 (16B): breaks the 256B-stride 16-way bank conflict
// of fragment loads down to 2-way (free, m136).
template <int K>
__global__ __launch_bounds__(256) void k_gemm_mfma(const float* __restrict__ X,
                                                   const uint32* __restrict__ Wtb,
                                                   uint32* __restrict__ outb, int nrows) {
    constexpr int KP = K + 8;
    __shared__ alignas(16) unsigned short Al[64 * KP];
    __shared__ alignas(16) unsigned short Bl[64 * KP];
    int tid = threadIdx.x;
    // stage Wtb (bf16 [64][K] packed uint [64][K/2]) into padded Bl
    for (int i = tid; i < 64 * (K / 2); i += 256) {
        int n = i / (K / 2), kp = i % (K / 2);
        *(uint32*)&Bl[n * KP + kp * 2] = Wtb[i];
    }
    // stage X tile (64 rows x K f32 -> bf16, padded rows)
    int r0 = blockIdx.x * 64;
    const float* Xb = X + (size_t)r0 * K;
    int limit = (nrows - r0) * K;
    for (int f = tid * 4; f < 64 * K; f += 1024) {
        float4 v = {0.f, 0.f, 0.f, 0.f};
        if (f + 3 < limit) v = *(const float4*)&Xb[f];
        int row = f / K, kpos = f % K;
        ushort4 pk;
        pk.x = (unsigned short)f2bf(v.x);
        pk.y = (unsigned short)f2bf(v.y);
        pk.z = (unsigned short)f2bf(v.z);
        pk.w = (unsigned short)f2bf(v.w);
        *(ushort4*)&Al[row * KP + kpos] = pk;
    }
    __syncthreads();
    int lane = tid & 63, wv = tid >> 6;
    int m = lane & 15, quad = lane >> 4;
    f32x4 acc0 = {0.f, 0.f, 0.f, 0.f}, acc1 = acc0, acc2 = acc0, acc3 = acc0;
    int arow = wv * 16 + m;
#pragma unroll
    for (int k0 = 0; k0 < K; k0 += 32) {
        int koff = k0 + quad * 8;
        bf16x8 a = *(const bf16x8*)&Al[arow * KP + koff];
        bf16x8 b0 = *(const bf16x8*)&Bl[(0 * 16 + m) * KP + koff];
        bf16x8 b1 = *(const bf16x8*)&Bl[(1 * 16 + m) * KP + koff];
        bf16x8 b2 = *(const bf16x8*)&Bl[(2 * 16 + m) * KP + koff];
        bf16x8 b3 = *(const bf16x8*)&Bl[(3 * 16 + m) * KP + koff];
        acc0 = __builtin_amdgcn_mfma_f32_16x16x32_bf16(a, b0, acc0, 0, 0, 0);
        acc1 = __builtin_amdgcn_mfma_f32_16x16x32_bf16(a, b1, acc1, 0, 0, 0);
        acc2 = __builtin_amdgcn_mfma_f32_16x16x32_bf16(a, b2, acc2, 0, 0, 0);
        acc3 = __builtin_amdgcn_mfma_f32_16x16x32_bf16(a, b3, acc3, 0, 0, 0);
    }
    // C/D layout: col = nt*16 + (lane&15), row = quad*4 + reg.
    // Pack adjacent cols (even lane + odd lane) into one uint bf16 pair.
    const float* accs[4] = {(const float*)&acc0, (const float*)&acc1,
                            (const float*)&acc2, (const float*)&acc3};
#pragma unroll
    for (int nt = 0; nt < 4; ++nt) {
#pragma unroll
        for (int reg = 0; reg < 4; ++reg) {
            float val = accs[nt][reg];
            float nxt = __shfl_down(val, 1);
            int row = r0 + wv * 16 + quad * 4 + reg;
            if (((m & 1) == 0) && row < nrows)
                outb[(size_t)row * 32 + nt * 8 + (m >> 1)] =
                    f2bf(val) | (f2bf(nxt) << 16);
        }
    }
}

// ---------- fused GCN aggregate + selfloop + BN + ReLU (+resid), bf16 ------
__global__ void k_gcn_gather(const uint32* __restrict__ hwb, const int* __restrict__ col,
                             const int* __restrict__ offs,
                             const float* __restrict__ dinv, const float* __restrict__ scale,
                             const float* __restrict__ shift, const float* __restrict__ resid,
                             float* __restrict__ out) {
    int node = blockIdx.x * 4 + (threadIdx.x >> 6);
    if (node >= NN) return;
    int lane = threadIdx.x & 63;
    int half = lane >> 5;
    int fl = lane & 31;                 // feature pair: {2fl, 2fl+1}
    int e0 = offs[node], e1 = offs[node + 1];
    float di = dinv[node];
    float ax = 0.f, ay = 0.f;
    for (int base = e0; base < e1; base += 64) {
        int m = e1 - base; if (m > 64) m = 64;
        int srcv = 0; float wv = 0.f;
        if (lane < m) { srcv = col[base + lane]; wv = dinv[srcv]; }
        int j = 0;
        for (; j + 4 <= m; j += 4) {
            int   sa = __shfl(srcv, j + half);
            int   sb = __shfl(srcv, j + 2 + half);
            float na = __shfl(wv, j + half);
            float nb = __shfl(wv, j + 2 + half);
            uint32 ua = hwb[(size_t)sa * 32 + fl];
            uint32 ub = hwb[(size_t)sb * 32 + fl];
            ax = fmaf(bf_lo(ua), na, ax); ay = fmaf(bf_hi(ua), na, ay);
            ax = fmaf(bf_lo(ub), nb, ax); ay = fmaf(bf_hi(ub), nb, ay);
        }
        for (; j < m; j += 2) {
            int   s = __shfl(srcv, j + half);
            float n = __shfl(wv, j + half);
            uint32 u = hwb[(size_t)s * 32 + fl];
            ax = fmaf(bf_lo(u), n, ax); ay = fmaf(bf_hi(u), n, ay);
        }
    }
    ax += __shfl(ax, fl + 32);
    ay += __shfl(ay, fl + 32);
    if (half == 0) {
        uint32 uself = hwb[(size_t)node * 32 + fl];
        float dii = di * di;
        float vx = fmaf(ax * di + bf_lo(uself) * dii, scale[2 * fl],     shift[2 * fl]);
        float vy = fmaf(ay * di + bf_hi(uself) * dii, scale[2 * fl + 1], shift[2 * fl + 1]);
        vx = fmaxf(vx, 0.f);
        vy = fmaxf(vy, 0.f);
        if (resid) {
            float2 rv = *(const float2*)&resid[(size_t)node * 64 + 2 * fl];
            vx += rv.x; vy += rv.y;
        }
        float2 o; o.x = vx; o.y = vy;
        *(float2*)&out[(size_t)node * 64 + 2 * fl] = o;
    }
}

// ---------------- pooling over sorted batch ----------------
__global__ void k_pool(const float* __restrict__ h, const int* __restrict__ batch,
                       float* __restrict__ msum, float* __restrict__ mmax,
                       float* __restrict__ gcnt) {
    int lane = threadIdx.x;  // 64
    int i0 = blockIdx.x * 128;
    int i1 = i0 + 128; if (i1 > NN) i1 = NN;
    int cur = batch[i0];
    float sum = 0.f, mx = 0.f; int c = 0;
    for (int i = i0; i < i1; ++i) {
        int g = batch[i];
        if (g != cur) {
            atomicAdd(&msum[cur * 64 + lane], sum);
            atomicMax((unsigned int*)&mmax[cur * 64 + lane], __float_as_uint(mx));
            if (lane == 0) atomicAdd(&gcnt[cur], (float)c);
            sum = 0.f; mx = 0.f; c = 0; cur = g;
        }
        float v = h[(long)i * 64 + lane];
        sum += v; mx = fmaxf(mx, v); ++c;
    }
    atomicAdd(&msum[cur * 64 + lane], sum);
    atomicMax((unsigned int*)&mmax[cur * 64 + lane], __float_as_uint(mx));
    if (lane == 0) atomicAdd(&gcnt[cur], (float)c);
}

// ---------------- MLP head, one block per graph ----------------
__global__ void k_head(const float* __restrict__ msum, const float* __restrict__ mmax,
                       const float* __restrict__ gcnt,
                       const float* __restrict__ Wh1, const float* __restrict__ bh1,
                       const float* __restrict__ Wh2, const float* __restrict__ bh2,
                       const float* __restrict__ Wh3, const float* __restrict__ bh3,
                       float* __restrict__ out) {
    int g = blockIdx.x, t = threadIdx.x;  // 64 threads
    __shared__ float hg[128];
    __shared__ float z1[64];
    __shared__ float z2[32];
    float c = fmaxf(gcnt[g], 1.f);
    hg[t]      = msum[g * 64 + t] / c;
    hg[64 + t] = mmax[g * 64 + t];
    __syncthreads();
    float acc = bh1[t];
#pragma unroll 8
    for (int k = 0; k < 128; ++k) acc = fmaf(hg[k], Wh1[k * 64 + t], acc);
    z1[t] = fmaxf(acc, 0.f);
    __syncthreads();
    if (t < 32) {
        float a2 = bh2[t];
#pragma unroll 8
        for (int k = 0; k < 64; ++k) a2 = fmaf(z1[k], Wh2[k * 32 + t], a2);
        z2[t] = fmaxf(a2, 0.f);
    }
    __syncthreads();
    if (t == 0) {
        float a3 = bh3[0];
        for (int k = 0; k < 32; ++k) a3 = fmaf(z2[k], Wh3[k], a3);
        out[g] = 1.f / (1.f + expf(-a3));
    }
}

// ---------------- launcher ----------------

static inline size_t alignup(size_t x) { return (x + 255) & ~(size_t)255; }

extern "C" void kernel_launch(void* const* d_in, const int* in_sizes, int n_in,
                              void* d_out, int out_size, void* d_ws, size_t ws_size,
                              hipStream_t stream) {
    const float* x   = (const float*)d_in[0];
    const int*   ei  = (const int*)d_in[1];
    const int*   bat = (const int*)d_in[2];
    const float* W1  = (const float*)d_in[3];
    const float* b1  = (const float*)d_in[4];
    const float* g1  = (const float*)d_in[5];
    const float* be1 = (const float*)d_in[6];
    const float* rm1 = (const float*)d_in[7];
    const float* rv1 = (const float*)d_in[8];
    const float* W2  = (const float*)d_in[9];
    const float* b2  = (const float*)d_in[10];
    const float* g2  = (const float*)d_in[11];
    const float* be2 = (const float*)d_in[12];
    const float* rm2 = (const float*)d_in[13];
    const float* rv2 = (const float*)d_in[14];
    const float* Wh1 = (const float*)d_in[15];
    const float* bh1 = (const float*)d_in[16];
    const float* Wh2 = (const float*)d_in[17];
    const float* bh2 = (const float*)d_in[18];
    const float* Wh3 = (const float*)d_in[19];
    const float* bh3 = (const float*)d_in[20];
    float* out = (float*)d_out;

    char* ws = (char*)d_ws;
    size_t o = 0;
    int*   bcnt   = (int*)(ws + o);  o = alignup(o + NBUK * 4);
    int*   bbase  = (int*)(ws + o);  o = alignup(o + (NBUK + 1) * 4);
    int*   gcur   = (int*)(ws + o);  o = alignup(o + NBUK * 4);
    int*   offs   = (int*)(ws + o);  o = alignup(o + (NN + 1) * 4);
    uint32* pairs = (uint32*)(ws + o); o = alignup(o + (size_t)EE * 4);
    int*   col    = (int*)(ws + o);  o = alignup(o + (size_t)EE * 4);
    float* dinv   = (float*)(ws + o); o = alignup(o + (size_t)NN * 4);
    float* scb    = (float*)(ws + o); o = alignup(o + 4 * 64 * 4);
    uint32* Wt1b  = (uint32*)(ws + o); o = alignup(o + 64 * (INF_ / 2) * 4);
    uint32* Wt2b  = (uint32*)(ws + o); o = alignup(o + 64 * (HID / 2) * 4);
    float* msum   = (float*)(ws + o);
    size_t pool_off = o;              o += (size_t)GG * 64 * 4;
    float* mmax   = (float*)(ws + o); o += (size_t)GG * 64 * 4;
    float* gcnt   = (float*)(ws + o); o += (size_t)GG * 4;
    size_t pool_bytes = o - pool_off; o = alignup(o);
    uint32* hwb   = (uint32*)(ws + o); o = alignup(o + (size_t)NN * 32 * 4);
    float* h      = (float*)(ws + o); o = alignup(o + (size_t)NN * 64 * 4);
    (void)ws_size; (void)n_in; (void)in_sizes; (void)out_size;

    hipMemsetAsync(bcnt, 0, NBUK * 4, stream);
    hipMemsetAsync(ws + pool_off, 0, pool_bytes, stream);

    k_precompute_bn<<<1, 64, 0, stream>>>(b1, g1, be1, rm1, rv1, b2, g2, be2, rm2, rv2, scb);
    k_wt<<<(64 * (INF_ / 2) + 255) / 256, 256, 0, stream>>>(W1, Wt1b, INF_);
    k_wt<<<(64 * (HID / 2) + 255) / 256, 256, 0, stream>>>(W2, Wt2b, HID);
    k_bhist<<<P1_TILES, 256, 0, stream>>>(ei, bcnt);
    k_bscan<<<1, 512, 0, stream>>>(bcnt, bbase, gcur, offs);
    k_p1<<<P1_TILES, 256, 0, stream>>>(ei, gcur, pairs);
    k_p2<<<NBUK, 256, 0, stream>>>(pairs, bbase, offs, dinv, col);

    // layer 1
    k_gemm_mfma<INF_><<<(NN + 63) / 64, 256, 0, stream>>>(x, Wt1b, hwb, NN);
    k_gcn_gather<<<(NN + 3) / 4, 256, 0, stream>>>(hwb, col, offs, dinv,
                                                   scb, scb + 64, nullptr, h);
    // layer 2 (residual, in-place into h)
    k_gemm_mfma<HID><<<(NN + 63) / 64, 256, 0, stream>>>(h, Wt2b, hwb, NN);
    k_gcn_gather<<<(NN + 3) / 4, 256, 0, stream>>>(hwb, col, offs, dinv,
                                                   scb + 128, scb + 192, h, h);
    // pooling + head
    k_pool<<<(NN + 127) / 128, 64, 0, stream>>>(h, bat, msum, mmax, gcnt);
    k_head<<<GG, 64, 0, stream>>>(msum, mmax, gcnt, Wh1, bh1, Wh2, bh2, Wh3, bh3, out);
}